// Round 9
// baseline (287.469 us; speedup 1.0000x reference)
//
#include <hip/hip_runtime.h>

// Ensemble of 8 LSTMs (H=64, input dim 1) over T=1024, B=128, then (B,T)@Wl^T+bl.
//
// v9 = v8 structure with 2-batch blocks for 2-blocks/CU co-residency.
//  - 512 blocks (8 L x 64 batch-pairs) x 256 threads (4 waves) -> 2048 waves,
//    2 blocks/CU, 2 INDEPENDENT waves/SIMD (separate barriers) so one block's
//    per-step stalls (LDS latency, MFMA deps, trans chain, barrier) are filled
//    by the other block's issue. v8 was 1 wave/SIMD: ~550/700 cyc exposed.
//  - A(16x64) rows m = h[batch m&1] (2 batches replicated 8x, bf16).
//    B = Whh rows [64g+16w+col], bf16, pre-scaled by 1/ln2 (tanh 2/ln2).
//    8 MFMAs/wave/step. D: col=unit-in-tile, row=4*kg+reg, batch=reg&1.
//    Active lanes kg<2 take reg kg -> all 4 gates of cell (batch kg, unit
//    16w+col) in-register; 1 cndmask select; 1 cell/lane on 32 lanes.
//  - h ping-pong in swizzled 16-slot LDS buffer (reads/writes <=2-way, free).
//  - 1 __syncthreads per step. h63 ring fp32 -> projection after loop.

#define LENA 8
#define NB 128
#define NT 1024
#define NH 64

typedef __attribute__((ext_vector_type(4))) float f32x4;
typedef __attribute__((ext_vector_type(8))) short bf16x8;

__device__ __forceinline__ short f2bf(float f) {
    unsigned u = __float_as_uint(f);
    unsigned r = (u + 0x7FFFu + ((u >> 16) & 1u)) >> 16;
    return (short)r;
}

__global__ __launch_bounds__(256, 2) void lstm_v9_kernel(
    const float* __restrict__ x, const float* __restrict__ hn,
    const float* __restrict__ Wih, const float* __restrict__ Whh,
    const float* __restrict__ bih, const float* __restrict__ bhh,
    const float* __restrict__ Wl, float* __restrict__ ws)
{
    __shared__ float x2[NT][2];                      // 8 KB
    __shared__ float ring[NT][2];                    // 8 KB: h63 history (fp32)
    __shared__ __align__(16) short hbuf[2][16][8];   // 512 B: ping-pong h, swizzled slots
    __shared__ float pws[2][2][8];                   // projection partials

    const int tid = threadIdx.x;
    const int w   = tid >> 6;        // wave 0..3: owns unit-tile w (units 16w..16w+15)
    const int l   = tid & 63;
    const int col = l & 15;          // unit-in-tile (D col / A row / B row)
    const int kg  = l >> 4;          // k-group; active kg<2 is also the lane's batch
    const int li  = blockIdx.x >> 6; // LSTM 0..7
    const int bg  = blockIdx.x & 63; // batch pair
    const int b0  = bg * 2;

    // ---- stage x: x2[t][bb] = x[b0+bb][t] ----
    for (int i = tid; i < 2 * NT; i += 256) {
        int bb = i >> 10, t = i & (NT - 1);
        x2[t][bb] = x[(size_t)(b0 + bb) * NT + t];
    }
    // ---- stage h0 into swizzled hbuf[0]: slot(b,s) = b*8 + (s ^ 2b) ----
    if (tid < 128) {
        int b = tid >> 6, u = tid & 63;
        float v = hn[((size_t)li * NB + b0 + b) * NH + u];
        int slot = b * 8 + ((u >> 3) ^ (2 * b));
        hbuf[0][slot][u & 7] = f2bf(v);
    }

    const float RLN2 = 1.44269504f;
    // ---- B-frags: bf[gate][khalf], row = 64g+16w+col, k = kh*32 + kg*8 + e ----
    bf16x8 bf[4][2];
    #pragma unroll
    for (int g = 0; g < 4; ++g) {
        const float sc = (g == 2) ? 2.0f * RLN2 : RLN2;
        const float* rp = Whh + ((size_t)li * 256 + 64 * g + 16 * w + col) * 64 + kg * 8;
        #pragma unroll
        for (int kh = 0; kh < 2; ++kh) {
            const float* q = rp + kh * 32;
            bf16x8 f;
            #pragma unroll
            for (int e = 0; e < 8; ++e) f[e] = f2bf(sc * q[e]);
            bf[g][kh] = f;
        }
    }
    // ---- per-lane cell constants: cell (b=kg, u=16w+col), kg<2 active ----
    const int u_c = 16 * w + col;
    float wih4[4];
    f32x4 cinit[4];     // bias splat as MFMA C-init
    #pragma unroll
    for (int g = 0; g < 4; ++g) {
        const float sc = (g == 2) ? 2.0f * RLN2 : RLN2;
        int rowc = li * 256 + 64 * g + u_c;
        wih4[g] = sc * Wih[rowc];
        float bv = sc * (bih[rowc] + bhh[rowc]);
        cinit[g][0] = bv; cinit[g][1] = bv; cinit[g][2] = bv; cinit[g][3] = bv;
    }

    // ---- A-read slots: A row m = h[batch m&1]; lane reads batch b_r = col&1 ----
    const int b_r = col & 1;
    const int s0 = b_r * 8 + (kg ^ (2 * b_r));          // khalf0: units 8kg..+8
    const int s1 = b_r * 8 + ((4 + kg) ^ (2 * b_r));    // khalf1: units 32+8kg..+8
    // ---- h-write slot for this lane's cell (kg<2) ----
    const int wslot = kg * 8 + ((u_c >> 3) ^ (2 * kg));
    const int wpos  = u_c & 7;
    const bool docell = (kg < 2);
    const bool isring = (u_c == 63) && docell;   // wave 3, col 15, kg<2

    const bool s_lo = (kg & 1) != 0;
    float cst = 0.0f;

    __syncthreads();

    #pragma unroll 2
    for (int t = 0; t < NT; ++t) {
        const int p = t & 1;
        bf16x8 a0 = *(const bf16x8*)&hbuf[p][s0][0];
        bf16x8 a1 = *(const bf16x8*)&hbuf[p][s1][0];

        f32x4 acc[4];
        #pragma unroll
        for (int g = 0; g < 4; ++g) {
            f32x4 a = __builtin_amdgcn_mfma_f32_16x16x32_bf16(a0, bf[g][0], cinit[g], 0, 0, 0);
            acc[g] = __builtin_amdgcn_mfma_f32_16x16x32_bf16(a1, bf[g][1], a, 0, 0, 0);
        }

        if (docell) {
            const float xsel = x2[t][kg];
            float gs0 = s_lo ? acc[0][1] : acc[0][0];
            float gs1 = s_lo ? acc[1][1] : acc[1][0];
            float gs2 = s_lo ? acc[2][1] : acc[2][0];
            float gs3 = s_lo ? acc[3][1] : acc[3][0];

            float gi = fmaf(xsel, wih4[0], gs0);
            float gf = fmaf(xsel, wih4[1], gs1);
            float gg = fmaf(xsel, wih4[2], gs2);
            float go = fmaf(xsel, wih4[3], gs3);

            float iv = __builtin_amdgcn_rcpf(1.0f + __builtin_amdgcn_exp2f(-gi));
            float fv = __builtin_amdgcn_rcpf(1.0f + __builtin_amdgcn_exp2f(-gf));
            float gt = fmaf(-2.0f, __builtin_amdgcn_rcpf(1.0f + __builtin_amdgcn_exp2f(gg)), 1.0f);
            float ov = __builtin_amdgcn_rcpf(1.0f + __builtin_amdgcn_exp2f(-go));
            cst = fmaf(fv, cst, iv * gt);
            float ct = fmaf(-2.0f, __builtin_amdgcn_rcpf(1.0f + __builtin_amdgcn_exp2f(2.88539008f * cst)), 1.0f);
            float hh = ov * ct;

            hbuf[p ^ 1][wslot][wpos] = f2bf(hh);
            if (isring) ring[t][kg] = hh;
        }
        __syncthreads();
    }

    // ---- projection: wave w -> batch b=w>>1, half p2=w&1 (512 t's) ----
    {
        const int b = w >> 1, p2 = w & 1;
        const int a = l & 7, ch = l >> 3;           // 8 outputs x 8 chunks of 64
        const int tb = p2 * 512 + ch * 64;
        const float* wlp = Wl + (size_t)a * NT + tb;
        float pacc = 0.0f;
        #pragma unroll 4
        for (int i = 0; i < 64; ++i)
            pacc = fmaf(ring[tb + i][b], wlp[i], pacc);
        pacc += __shfl_xor(pacc, 8);
        pacc += __shfl_xor(pacc, 16);
        pacc += __shfl_xor(pacc, 32);
        if (l < 8) pws[b][p2][a] = pacc;
    }
    __syncthreads();
    if (tid < 16) {
        int b = tid >> 3, a = tid & 7;
        ws[((size_t)blockIdx.x * 2 + b) * 8 + a] = pws[b][0][a] + pws[b][1][a];
    }
}

__global__ __launch_bounds__(256) void reduce_kernel(
    const float* __restrict__ ws, const float* __restrict__ bl, float* __restrict__ out)
{
    int tid = blockIdx.x * 256 + threadIdx.x;    // 0..1023
    if (tid >= NB * LENA) return;
    int b = tid >> 3, a = tid & 7;
    int bg = b >> 1, bb = b & 1;
    float s = bl[a];
    #pragma unroll
    for (int li = 0; li < LENA; ++li)
        s += ws[(((size_t)li * 64 + bg) * 2 + bb) * 8 + a];
    out[tid] = s;
}

extern "C" void kernel_launch(void* const* d_in, const int* in_sizes, int n_in,
                              void* d_out, int out_size, void* d_ws, size_t ws_size,
                              hipStream_t stream) {
    const float* x   = (const float*)d_in[0];
    const float* hn  = (const float*)d_in[1];
    const float* Wih = (const float*)d_in[2];
    const float* Whh = (const float*)d_in[3];
    const float* bih = (const float*)d_in[4];
    const float* bhh = (const float*)d_in[5];
    const float* Wl  = (const float*)d_in[6];
    const float* bl  = (const float*)d_in[7];
    float* out = (float*)d_out;
    float* ws  = (float*)d_ws;   // 512*2*8*4 = 32 KB

    lstm_v9_kernel<<<dim3(512), dim3(256), 0, stream>>>(x, hn, Wih, Whh, bih, bhh, Wl, ws);
    reduce_kernel<<<dim3(4), dim3(256), 0, stream>>>(ws, bl, out);
}

// Round 10
// 266.388 us; speedup vs baseline: 1.0791x; 1.0791x over previous
//
#include <hip/hip_runtime.h>

// Ensemble of 8 LSTMs (H=64, input dim 1) over T=1024, B=128, then (B,T)@Wl^T+bl.
//
// v10 = v9 (2-batch blocks, 2 blocks/CU, 2 waves/SIMD) with issue trimming.
//  - v9 measured ~95% issue-bound per SIMD (VALU 431 + MFMA 272 of 743 cyc/step).
//  - Cuts: no divergent cell branch (all lanes compute with bb=kg&1; kg/kg+2
//    duplicate-write identical values - benign), 1-instr v_cvt_pk_bf16_f32 for
//    the h pack, single cndmask select per gate, straight-line unroll-2 body.
//  - Math identical to v9: A rows = h[batch m&1] (bf16, dup8); B = Whh bf16
//    pre-scaled by 1/ln2 (tanh gate 2/ln2); bias in MFMA C-init; 8 MFMA/wave;
//    D col=unit, batch=reg&1; 1 barrier/step; h63 ring -> post-loop projection.

#define LENA 8
#define NB 128
#define NT 1024
#define NH 64

typedef __attribute__((ext_vector_type(4))) float f32x4;
typedef __attribute__((ext_vector_type(8))) short bf16x8;

__device__ __forceinline__ short f2bf(float f) {
    unsigned u = __float_as_uint(f);
    unsigned r = (u + 0x7FFFu + ((u >> 16) & 1u)) >> 16;
    return (short)r;
}

__global__ __launch_bounds__(256, 2) void lstm_v10_kernel(
    const float* __restrict__ x, const float* __restrict__ hn,
    const float* __restrict__ Wih, const float* __restrict__ Whh,
    const float* __restrict__ bih, const float* __restrict__ bhh,
    const float* __restrict__ Wl, float* __restrict__ ws)
{
    __shared__ float x2[NT][2];                      // 8 KB
    __shared__ float ring[NT][2];                    // 8 KB: h63 history
    __shared__ __align__(16) short hbuf[2][16][8];   // 512 B: ping-pong h, swizzled slots
    __shared__ float pws[2][2][8];                   // projection partials

    const int tid = threadIdx.x;
    const int w   = tid >> 6;        // wave 0..3: owns unit-tile w
    const int l   = tid & 63;
    const int col = l & 15;          // unit-in-tile (A/B row, D col)
    const int kg  = l >> 4;          // k-group
    const int bb  = kg & 1;          // this lane's batch (kg and kg+2 duplicate)
    const int li  = blockIdx.x >> 6; // LSTM 0..7
    const int bg  = blockIdx.x & 63; // batch pair
    const int b0  = bg * 2;

    // ---- stage x ----
    for (int i = tid; i < 2 * NT; i += 256) {
        int bx = i >> 10, t = i & (NT - 1);
        x2[t][bx] = x[(size_t)(b0 + bx) * NT + t];
    }
    // ---- stage h0 into swizzled hbuf[0]: slot(b,s) = b*8 + (s ^ 2b) ----
    if (tid < 128) {
        int b = tid >> 6, u = tid & 63;
        float v = hn[((size_t)li * NB + b0 + b) * NH + u];
        int slot = b * 8 + ((u >> 3) ^ (2 * b));
        hbuf[0][slot][u & 7] = f2bf(v);
    }

    const float RLN2 = 1.44269504f;
    // ---- B-frags: bf[gate][khalf], row = 64g+16w+col, k = kh*32 + kg*8 + e ----
    bf16x8 bf[4][2];
    #pragma unroll
    for (int g = 0; g < 4; ++g) {
        const float sc = (g == 2) ? 2.0f * RLN2 : RLN2;
        const float* rp = Whh + ((size_t)li * 256 + 64 * g + 16 * w + col) * 64 + kg * 8;
        #pragma unroll
        for (int kh = 0; kh < 2; ++kh) {
            const float* q = rp + kh * 32;
            bf16x8 f;
            #pragma unroll
            for (int e = 0; e < 8; ++e) f[e] = f2bf(sc * q[e]);
            bf[g][kh] = f;
        }
    }
    // ---- per-lane cell constants: cell (b=bb, u=16w+col) ----
    const int u_c = 16 * w + col;
    float wih4[4];
    f32x4 cinit[4];
    #pragma unroll
    for (int g = 0; g < 4; ++g) {
        const float sc = (g == 2) ? 2.0f * RLN2 : RLN2;
        int rowc = li * 256 + 64 * g + u_c;
        wih4[g] = sc * Wih[rowc];
        float bv = sc * (bih[rowc] + bhh[rowc]);
        cinit[g][0] = bv; cinit[g][1] = bv; cinit[g][2] = bv; cinit[g][3] = bv;
    }

    // ---- A-read slots: A row m = h[batch m&1]; lane reads batch b_r = col&1 ----
    const int b_r = col & 1;
    const int s0 = b_r * 8 + (kg ^ (2 * b_r));          // khalf0
    const int s1 = b_r * 8 + ((4 + kg) ^ (2 * b_r));    // khalf1
    // ---- h-write slot (batch-indexed: kg and kg+2 write same addr/value) ----
    const int wslot = bb * 8 + ((u_c >> 3) ^ (2 * bb));
    const int wpos  = u_c & 7;
    const bool isring = (u_c == 63);   // 4 lanes: (kg,bb) dup pairs

    float cst = 0.0f;

    __syncthreads();

    #pragma unroll 2
    for (int t = 0; t < NT; ++t) {
        const int p = t & 1;
        bf16x8 a0 = *(const bf16x8*)&hbuf[p][s0][0];
        bf16x8 a1 = *(const bf16x8*)&hbuf[p][s1][0];
        const float xv = x2[t][bb];

        f32x4 acc[4];
        #pragma unroll
        for (int g = 0; g < 4; ++g) {
            f32x4 a = __builtin_amdgcn_mfma_f32_16x16x32_bf16(a0, bf[g][0], cinit[g], 0, 0, 0);
            acc[g] = __builtin_amdgcn_mfma_f32_16x16x32_bf16(a1, bf[g][1], a, 0, 0, 0);
        }

        // select reg bb (batch) per gate; add x term
        float gi = fmaf(xv, wih4[0], bb ? acc[0][1] : acc[0][0]);
        float gf = fmaf(xv, wih4[1], bb ? acc[1][1] : acc[1][0]);
        float gg = fmaf(xv, wih4[2], bb ? acc[2][1] : acc[2][0]);
        float go = fmaf(xv, wih4[3], bb ? acc[3][1] : acc[3][0]);

        float iv = __builtin_amdgcn_rcpf(1.0f + __builtin_amdgcn_exp2f(-gi));
        float fv = __builtin_amdgcn_rcpf(1.0f + __builtin_amdgcn_exp2f(-gf));
        float gt = fmaf(-2.0f, __builtin_amdgcn_rcpf(1.0f + __builtin_amdgcn_exp2f(gg)), 1.0f);
        float ov = __builtin_amdgcn_rcpf(1.0f + __builtin_amdgcn_exp2f(-go));
        cst = fmaf(fv, cst, iv * gt);
        float ct = fmaf(-2.0f, __builtin_amdgcn_rcpf(1.0f + __builtin_amdgcn_exp2f(2.88539008f * cst)), 1.0f);
        float hh = ov * ct;

        unsigned pk;
        asm("v_cvt_pk_bf16_f32 %0, %1, %2" : "=v"(pk) : "v"(hh), "v"(hh));
        hbuf[p ^ 1][wslot][wpos] = (short)(pk & 0xffffu);
        if (isring) ring[t][bb] = hh;
        __syncthreads();
    }

    // ---- projection: wave w -> batch b=w>>1, half p2=w&1 ----
    {
        const int b = w >> 1, p2 = w & 1;
        const int a = l & 7, ch = l >> 3;
        const int tb = p2 * 512 + ch * 64;
        const float* wlp = Wl + (size_t)a * NT + tb;
        float pacc = 0.0f;
        #pragma unroll 4
        for (int i = 0; i < 64; ++i)
            pacc = fmaf(ring[tb + i][b], wlp[i], pacc);
        pacc += __shfl_xor(pacc, 8);
        pacc += __shfl_xor(pacc, 16);
        pacc += __shfl_xor(pacc, 32);
        if (l < 8) pws[b][p2][a] = pacc;
    }
    __syncthreads();
    if (tid < 16) {
        int b = tid >> 3, a = tid & 7;
        ws[((size_t)blockIdx.x * 2 + b) * 8 + a] = pws[b][0][a] + pws[b][1][a];
    }
}

__global__ __launch_bounds__(256) void reduce_kernel(
    const float* __restrict__ ws, const float* __restrict__ bl, float* __restrict__ out)
{
    int tid = blockIdx.x * 256 + threadIdx.x;    // 0..1023
    if (tid >= NB * LENA) return;
    int b = tid >> 3, a = tid & 7;
    int bg = b >> 1, bx = b & 1;
    float s = bl[a];
    #pragma unroll
    for (int li = 0; li < LENA; ++li)
        s += ws[(((size_t)li * 64 + bg) * 2 + bx) * 8 + a];
    out[tid] = s;
}

extern "C" void kernel_launch(void* const* d_in, const int* in_sizes, int n_in,
                              void* d_out, int out_size, void* d_ws, size_t ws_size,
                              hipStream_t stream) {
    const float* x   = (const float*)d_in[0];
    const float* hn  = (const float*)d_in[1];
    const float* Wih = (const float*)d_in[2];
    const float* Whh = (const float*)d_in[3];
    const float* bih = (const float*)d_in[4];
    const float* bhh = (const float*)d_in[5];
    const float* Wl  = (const float*)d_in[6];
    const float* bl  = (const float*)d_in[7];
    float* out = (float*)d_out;
    float* ws  = (float*)d_ws;   // 512*2*8*4 = 32 KB

    lstm_v10_kernel<<<dim3(512), dim3(256), 0, stream>>>(x, hn, Wih, Whh, bih, bhh, Wl, ws);
    reduce_kernel<<<dim3(4), dim3(256), 0, stream>>>(ws, bl, out);
}